// Round 1
// baseline (16301.376 us; speedup 1.0000x reference)
//
#include <hip/hip_runtime.h>
#include <hip/hip_bf16.h>

typedef unsigned short u16;
typedef short bf16x8 __attribute__((ext_vector_type(8)));
typedef float f32x4 __attribute__((ext_vector_type(4)));

// ---------- bf16 helpers ----------
__device__ inline float bflo(unsigned int w) { union { float f; unsigned int i; } c; c.i = w << 16; return c.f; }
__device__ inline float bfhi(unsigned int w) { union { float f; unsigned int i; } c; c.i = w & 0xffff0000u; return c.f; }
__device__ inline float bf2f(u16 u) { union { float f; unsigned int i; } c; c.i = ((unsigned int)u) << 16; return c.f; }
__device__ inline u16 f2bf(float f) {
    union { float f; unsigned int i; } c; c.f = f;
    unsigned int r = c.i + 0x7FFFu + ((c.i >> 16) & 1u);  // RNE
    return (u16)(r >> 16);
}
__device__ inline void unpack8(float* dst, uint4 u) {
    dst[0] = bflo(u.x); dst[1] = bfhi(u.x);
    dst[2] = bflo(u.y); dst[3] = bfhi(u.y);
    dst[4] = bflo(u.z); dst[5] = bfhi(u.z);
    dst[6] = bflo(u.w); dst[7] = bfhi(u.w);
}

__device__ inline float wave_sum(float v) {
#pragma unroll
    for (int off = 32; off; off >>= 1) v += __shfl_down(v, off);
    return v;
}

// ---------- convert token_emb -> bf16 (V*D = 4096*1024) ----------
__global__ __launch_bounds__(256) void k_cvt(const float* __restrict__ in, u16* __restrict__ out) {
    int i = blockIdx.x * 256 + threadIdx.x;  // over n/4
    float4 v = ((const float4*)in)[i];
    ushort4 o;
    o.x = f2bf(v.x); o.y = f2bf(v.y); o.z = f2bf(v.z); o.w = f2bf(v.w);
    ((ushort4*)out)[i] = o;
}

// ---------- transpose + convert: in fp32 (R,C) -> out bf16 (C,R), z = layer ----------
__global__ __launch_bounds__(256) void k_transpose(const float* __restrict__ in, u16* __restrict__ out, int R, int C) {
    __shared__ float tile[32][33];
    const float* inL = in + (size_t)blockIdx.z * R * C;
    u16* outL = out + (size_t)blockIdx.z * R * C;
    int cb = blockIdx.x * 32, rb = blockIdx.y * 32;
    int tx = threadIdx.x, ty = threadIdx.y;  // (32,8)
#pragma unroll
    for (int i = 0; i < 32; i += 8)
        tile[ty + i][tx] = inL[(size_t)(rb + ty + i) * C + cb + tx];
    __syncthreads();
#pragma unroll
    for (int i = 0; i < 32; i += 8)
        outL[(size_t)(cb + ty + i) * R + rb + tx] = f2bf(tile[tx][ty + i]);
}

// ---------- embedding: x[m,:] = token_emb[ids[m],:] + pos_emb[m%T,:] ----------
__global__ __launch_bounds__(256) void k_embed(const int* __restrict__ ids, const float* __restrict__ emb,
                                               const float* __restrict__ pos, float* __restrict__ x) {
    int i = blockIdx.x * 256 + threadIdx.x;  // over M*D/4 = 2,097,152
    int m = i >> 8;                          // D/4 = 256
    int d4 = i & 255;
    int t = m & 2047;
    int id = ids[m];
    float4 e = ((const float4*)(emb + (size_t)id * 1024))[d4];
    float4 p = ((const float4*)(pos + (size_t)t * 1024))[d4];
    float4 r; r.x = e.x + p.x; r.y = e.y + p.y; r.z = e.z + p.z; r.w = e.w + p.w;
    ((float4*)(x + (size_t)m * 1024))[d4] = r;
}

// ---------- layernorm: fp32 in (row of 1024) -> bf16 out ----------
__global__ __launch_bounds__(256) void k_ln(const float* __restrict__ in, const float* __restrict__ w,
                                            const float* __restrict__ b, u16* __restrict__ out) {
    int row = blockIdx.x, tid = threadIdx.x;
    float4 v = ((const float4*)(in + (size_t)row * 1024))[tid];
    float s = v.x + v.y + v.z + v.w;
    float ss = v.x * v.x + v.y * v.y + v.z * v.z + v.w * v.w;
    s = wave_sum(s); ss = wave_sum(ss);
    __shared__ float rs[4], rss[4];
    int wid = tid >> 6, lane = tid & 63;
    if (lane == 0) { rs[wid] = s; rss[wid] = ss; }
    __syncthreads();
    s = rs[0] + rs[1] + rs[2] + rs[3];
    ss = rss[0] + rss[1] + rss[2] + rss[3];
    float mu = s * (1.0f / 1024.0f);
    float var = ss * (1.0f / 1024.0f) - mu * mu;
    float inv = rsqrtf(var + 1e-5f);
    float4 wv = ((const float4*)w)[tid], bv = ((const float4*)b)[tid];
    ushort4 o;
    o.x = f2bf((v.x - mu) * inv * wv.x + bv.x);
    o.y = f2bf((v.y - mu) * inv * wv.y + bv.y);
    o.z = f2bf((v.z - mu) * inv * wv.z + bv.z);
    o.w = f2bf((v.w - mu) * inv * wv.w + bv.w);
    *(ushort4*)(out + (size_t)row * 1024 + tid * 4) = o;
}

// ---------- MFMA GEMM: C(M,N) = A(M,K) @ Bt(N,K)^T [+bias][gelu][+res] ----------
// 128x128 tile, BK=32, 256 threads = 4 waves (2x2 of 64x64), 4x4 mfma subtiles per wave.
template <bool OUT_BF16, bool GELU, bool RES, bool BIAS>
__global__ __launch_bounds__(256, 2) void k_gemm(const u16* __restrict__ A, const u16* __restrict__ Bt,
                                                 const float* __restrict__ bias, const float* __restrict__ res,
                                                 float* __restrict__ outF, u16* __restrict__ outB,
                                                 int M, int N, int K) {
    __shared__ __align__(16) u16 ldsA[128 * 32];
    __shared__ __align__(16) u16 ldsB[128 * 32];
    int tid = threadIdx.x;
    int wave = tid >> 6, lane = tid & 63;
    int quad = lane >> 4, l15 = lane & 15;
    int m0 = blockIdx.y * 128, n0 = blockIdx.x * 128;
    int wm = (wave >> 1) * 64, wn = (wave & 1) * 64;

    f32x4 acc[4][4];
#pragma unroll
    for (int i = 0; i < 4; i++)
#pragma unroll
        for (int j = 0; j < 4; j++) acc[i][j] = (f32x4){0.f, 0.f, 0.f, 0.f};

    int r0 = tid >> 2, c0 = (tid & 3) * 8;  // rows 0..63
    int r1 = r0 + 64;                        // rows 64..127
    const u16* pa0 = A + (size_t)(m0 + r0) * K + c0;
    const u16* pa1 = A + (size_t)(m0 + r1) * K + c0;
    const u16* pb0 = Bt + (size_t)(n0 + r0) * K + c0;
    const u16* pb1 = Bt + (size_t)(n0 + r1) * K + c0;

    for (int k0 = 0; k0 < K; k0 += 32) {
        uint4 a0 = *(const uint4*)(pa0 + k0);
        uint4 a1 = *(const uint4*)(pa1 + k0);
        uint4 b0 = *(const uint4*)(pb0 + k0);
        uint4 b1 = *(const uint4*)(pb1 + k0);
        __syncthreads();
        *(uint4*)(ldsA + r0 * 32 + c0) = a0;
        *(uint4*)(ldsA + r1 * 32 + c0) = a1;
        *(uint4*)(ldsB + r0 * 32 + c0) = b0;
        *(uint4*)(ldsB + r1 * 32 + c0) = b1;
        __syncthreads();
        bf16x8 af[4], bfr[4];
#pragma unroll
        for (int i = 0; i < 4; i++) af[i] = *(const bf16x8*)(ldsA + (wm + i * 16 + l15) * 32 + quad * 8);
#pragma unroll
        for (int j = 0; j < 4; j++) bfr[j] = *(const bf16x8*)(ldsB + (wn + j * 16 + l15) * 32 + quad * 8);
#pragma unroll
        for (int i = 0; i < 4; i++)
#pragma unroll
            for (int j = 0; j < 4; j++)
                acc[i][j] = __builtin_amdgcn_mfma_f32_16x16x32_bf16(af[i], bfr[j], acc[i][j], 0, 0, 0);
    }

#pragma unroll
    for (int j = 0; j < 4; j++) {
        int col = n0 + wn + j * 16 + l15;
        float bj = BIAS ? bias[col] : 0.f;
#pragma unroll
        for (int i = 0; i < 4; i++) {
#pragma unroll
            for (int r = 0; r < 4; r++) {
                int row = m0 + wm + i * 16 + quad * 4 + r;
                float v = acc[i][j][r] + bj;
                if (GELU) v = 0.5f * v * (1.0f + erff(v * 0.70710678f));
                if (RES) v += res[(size_t)row * N + col];
                if (OUT_BF16) outB[(size_t)row * N + col] = f2bf(v);
                else outF[(size_t)row * N + col] = v;
            }
        }
    }
}

// ---------- attention: scalar flash, thread per q-row ----------
// qkv bf16 (M, 3072): q at col h*64, k at 1024+h*64, v at 2048+h*64. out bf16 (M, 1024).
__global__ __launch_bounds__(256, 2) void k_attn(const u16* __restrict__ qkv, u16* __restrict__ out) {
    int b = blockIdx.y >> 4, h = blockIdx.y & 15;
    int q0 = blockIdx.x * 256;
    int tid = threadIdx.x;
    int tq = q0 + tid;
    __shared__ float kk[64][64];
    __shared__ float vv[64][64];

    const u16* qrow = qkv + (size_t)(b * 2048 + tq) * 3072 + h * 64;
    float q[64], o[64];
#pragma unroll
    for (int c = 0; c < 8; c++) {
        uint4 u = *(const uint4*)(qrow + c * 8);
        float tmp[8]; unpack8(tmp, u);
#pragma unroll
        for (int e = 0; e < 8; e++) q[c * 8 + e] = tmp[e] * 0.125f;
    }
#pragma unroll
    for (int d = 0; d < 64; d++) o[d] = 0.f;
    float mrun = -3e38f, lrun = 0.f;

    int sr = tid >> 2, sd = (tid & 3) * 16;
    for (int kt = 0; kt < q0 + 256; kt += 64) {
        __syncthreads();
        {
            const u16* kp = qkv + (size_t)(b * 2048 + kt + sr) * 3072 + 1024 + h * 64 + sd;
            uint4 u0 = *(const uint4*)(kp);
            uint4 u1 = *(const uint4*)(kp + 8);
            unpack8(&kk[sr][sd], u0); unpack8(&kk[sr][sd + 8], u1);
            uint4 w0 = *(const uint4*)(kp + 1024);
            uint4 w1 = *(const uint4*)(kp + 1032);
            unpack8(&vv[sr][sd], w0); unpack8(&vv[sr][sd + 8], w1);
        }
        __syncthreads();
        int jmax = tq - kt + 1;
        if (jmax > 64) jmax = 64;
        for (int j = 0; j < jmax; j++) {
            float s = 0.f;
#pragma unroll
            for (int d = 0; d < 64; d++) s = fmaf(q[d], kk[j][d], s);
            if (s > mrun) {
                float alpha = __expf(mrun - s);
                mrun = s;
                lrun = lrun * alpha + 1.0f;
#pragma unroll
                for (int d = 0; d < 64; d++) o[d] = o[d] * alpha + vv[j][d];
            } else {
                float p = __expf(s - mrun);
                lrun += p;
#pragma unroll
                for (int d = 0; d < 64; d++) o[d] = fmaf(p, vv[j][d], o[d]);
            }
        }
    }
    float inv = 1.0f / lrun;
    unsigned int* orow = (unsigned int*)(out + (size_t)(b * 2048 + tq) * 1024 + h * 64);
#pragma unroll
    for (int c = 0; c < 32; c++)
        orow[c] = ((unsigned int)f2bf(o[2 * c + 1] * inv) << 16) | (unsigned int)f2bf(o[2 * c] * inv);
}

// ---------- CE per row: ce[row] = (tgt==0) ? 0 : -(logit[tgt] - max - log(sumexp)) ----------
__global__ __launch_bounds__(256) void k_ce(const float* __restrict__ logits, const int* __restrict__ targets,
                                            float* __restrict__ ce) {
    int row = blockIdx.x, tid = threadIdx.x;
    const float4* lr = (const float4*)(logits + (size_t)row * 4096);
    float4 v[4];
#pragma unroll
    for (int c = 0; c < 4; c++) v[c] = lr[tid + c * 256];
    float mx = -3e38f;
#pragma unroll
    for (int c = 0; c < 4; c++) mx = fmaxf(mx, fmaxf(fmaxf(v[c].x, v[c].y), fmaxf(v[c].z, v[c].w)));
#pragma unroll
    for (int off = 32; off; off >>= 1) mx = fmaxf(mx, __shfl_xor(mx, off));
    __shared__ float rm[4], rsum[4];
    int wid = tid >> 6, lane = tid & 63;
    if (lane == 0) rm[wid] = mx;
    __syncthreads();
    mx = fmaxf(fmaxf(rm[0], rm[1]), fmaxf(rm[2], rm[3]));
    float se = 0.f;
#pragma unroll
    for (int c = 0; c < 4; c++)
        se += __expf(v[c].x - mx) + __expf(v[c].y - mx) + __expf(v[c].z - mx) + __expf(v[c].w - mx);
#pragma unroll
    for (int off = 32; off; off >>= 1) se += __shfl_xor(se, off);
    if (lane == 0) rsum[wid] = se;
    __syncthreads();
    if (tid == 0) {
        se = rsum[0] + rsum[1] + rsum[2] + rsum[3];
        int tgt = targets[row];
        float nll = -(logits[(size_t)row * 4096 + tgt] - mx - logf(se));
        ce[row] = (tgt == 0) ? 0.f : nll;
    }
}

// ---------- final loss: detect mask dtype (u8 vs i32), weighted reduce ----------
__global__ __launch_bounds__(256) void k_loss(const float* __restrict__ ce, const int* __restrict__ vmask,
                                              float* __restrict__ out) {
    int tid = threadIdx.x;
    int wid = tid >> 6, lane = tid & 63;
    // First 2048 int32 words = first 8192 bytes: safe to read under either dtype.
    int bad = 0;
    for (int i = tid; i < 2048; i += 256) {
        unsigned int w = ((const unsigned int*)vmask)[i];
        if (w > 1u) bad = 1;
    }
#pragma unroll
    for (int off = 32; off; off >>= 1) bad |= __shfl_xor(bad, off);
    __shared__ int sb[4];
    if (lane == 0) sb[wid] = bad;
    __syncthreads();
    bad = sb[0] | sb[1] | sb[2] | sb[3];  // 1 => mask is packed bytes (bool)

    float s1 = 0.f, s2 = 0.f;
    if (bad) {
        const unsigned char* mb = (const unsigned char*)vmask;
        for (int i = tid; i < 8192; i += 256) {
            float w = 1.0f + 4.0f * (mb[i] != 0);
            s1 += ce[i] * w; s2 += w;
        }
    } else {
        for (int i = tid; i < 8192; i += 256) {
            float w = 1.0f + 4.0f * (vmask[i] != 0);
            s1 += ce[i] * w; s2 += w;
        }
    }
#pragma unroll
    for (int off = 32; off; off >>= 1) { s1 += __shfl_down(s1, off); s2 += __shfl_down(s2, off); }
    __shared__ float r1[4], r2[4];
    if (lane == 0) { r1[wid] = s1; r2[wid] = s2; }
    __syncthreads();
    if (tid == 0) out[0] = (r1[0] + r1[1] + r1[2] + r1[3]) / (r2[0] + r2[1] + r2[2] + r2[3]);
}

extern "C" void kernel_launch(void* const* d_in, const int* in_sizes, int n_in,
                              void* d_out, int out_size, void* d_ws, size_t ws_size,
                              hipStream_t stream) {
    const int* input_ids = (const int*)d_in[0];
    const int* targets = (const int*)d_in[1];
    const int* vmask = (const int*)d_in[2];
    const float* token_emb = (const float*)d_in[3];
    const float* pos_emb = (const float*)d_in[4];
    const float* ln1_w = (const float*)d_in[5];
    const float* ln1_b = (const float*)d_in[6];
    const float* wqkv = (const float*)d_in[7];
    const float* bqkv = (const float*)d_in[8];
    const float* wproj = (const float*)d_in[9];
    const float* bproj = (const float*)d_in[10];
    const float* ln2_w = (const float*)d_in[11];
    const float* ln2_b = (const float*)d_in[12];
    const float* w1 = (const float*)d_in[13];
    const float* b1 = (const float*)d_in[14];
    const float* w2 = (const float*)d_in[15];
    const float* b2 = (const float*)d_in[16];
    const float* lnf_w = (const float*)d_in[17];
    const float* lnf_b = (const float*)d_in[18];

    char* p = (char*)d_ws;
    u16* embb = (u16*)p;   p += (size_t)4096 * 1024 * 2;
    u16* wqkvt = (u16*)p;  p += (size_t)8 * 3072 * 1024 * 2;
    u16* wprojt = (u16*)p; p += (size_t)8 * 1024 * 1024 * 2;
    u16* w1t = (u16*)p;    p += (size_t)8 * 4096 * 1024 * 2;
    u16* w2t = (u16*)p;    p += (size_t)8 * 1024 * 4096 * 2;
    float* xw = (float*)p; p += (size_t)8192 * 1024 * 4;
    u16* hb = (u16*)p;     p += (size_t)8192 * 1024 * 2;
    u16* qkvb = (u16*)p;   p += (size_t)8192 * 3072 * 2;
    u16* attnb = (u16*)p;  p += (size_t)8192 * 1024 * 2;
    u16* ffb = (u16*)p;    p += (size_t)8192 * 4096 * 2;
    float* cerow = (float*)p; p += 8192 * 4;

    float* logits = (float*)d_out;

    // weight prep (bf16, transposed to (N,K))
    k_cvt<<<4096, 256, 0, stream>>>(token_emb, embb);
    dim3 tb(32, 8);
    k_transpose<<<dim3(96, 32, 8), tb, 0, stream>>>(wqkv, wqkvt, 1024, 3072);
    k_transpose<<<dim3(32, 32, 8), tb, 0, stream>>>(wproj, wprojt, 1024, 1024);
    k_transpose<<<dim3(128, 32, 8), tb, 0, stream>>>(w1, w1t, 1024, 4096);
    k_transpose<<<dim3(32, 128, 8), tb, 0, stream>>>(w2, w2t, 4096, 1024);

    k_embed<<<8192, 256, 0, stream>>>(input_ids, token_emb, pos_emb, xw);

    for (int l = 0; l < 8; l++) {
        k_ln<<<8192, 256, 0, stream>>>(xw, ln1_w + l * 1024, ln1_b + l * 1024, hb);
        k_gemm<true, false, false, true><<<dim3(24, 64), 256, 0, stream>>>(
            hb, wqkvt + (size_t)l * 3072 * 1024, bqkv + l * 3072, nullptr, nullptr, qkvb, 8192, 3072, 1024);
        k_attn<<<dim3(8, 64), 256, 0, stream>>>(qkvb, attnb);
        k_gemm<false, false, true, true><<<dim3(8, 64), 256, 0, stream>>>(
            attnb, wprojt + (size_t)l * 1024 * 1024, bproj + l * 1024, xw, xw, nullptr, 8192, 1024, 1024);
        k_ln<<<8192, 256, 0, stream>>>(xw, ln2_w + l * 1024, ln2_b + l * 1024, hb);
        k_gemm<true, true, false, true><<<dim3(32, 64), 256, 0, stream>>>(
            hb, w1t + (size_t)l * 4096 * 1024, b1 + l * 4096, nullptr, nullptr, ffb, 8192, 4096, 1024);
        k_gemm<false, false, true, true><<<dim3(8, 64), 256, 0, stream>>>(
            ffb, w2t + (size_t)l * 1024 * 4096, b2 + l * 1024, xw, xw, nullptr, 8192, 1024, 4096);
    }

    k_ln<<<8192, 256, 0, stream>>>(xw, lnf_w, lnf_b, hb);
    k_gemm<false, false, false, false><<<dim3(32, 64), 256, 0, stream>>>(
        hb, embb, nullptr, nullptr, logits, nullptr, 8192, 4096, 1024);

    k_ce<<<8192, 256, 0, stream>>>(logits, targets, cerow);
    k_loss<<<1, 256, 0, stream>>>(cerow, vmask, logits + (size_t)8192 * 4096);
}

// Round 2
// 5137.248 us; speedup vs baseline: 3.1732x; 3.1732x over previous
//
#include <hip/hip_runtime.h>
#include <hip/hip_bf16.h>

typedef unsigned short u16;
typedef short bf16x8 __attribute__((ext_vector_type(8)));
typedef float f32x4 __attribute__((ext_vector_type(4)));

// ---------- bf16 helpers ----------
__device__ inline float bflo(unsigned int w) { union { float f; unsigned int i; } c; c.i = w << 16; return c.f; }
__device__ inline float bfhi(unsigned int w) { union { float f; unsigned int i; } c; c.i = w & 0xffff0000u; return c.f; }
__device__ inline u16 f2bf(float f) {
    union { float f; unsigned int i; } c; c.f = f;
    unsigned int r = c.i + 0x7FFFu + ((c.i >> 16) & 1u);  // RNE
    return (u16)(r >> 16);
}

__device__ inline float wave_sum(float v) {
#pragma unroll
    for (int off = 32; off; off >>= 1) v += __shfl_down(v, off);
    return v;
}

// ---------- convert token_emb -> bf16 (V*D = 4096*1024) ----------
__global__ __launch_bounds__(256) void k_cvt(const float* __restrict__ in, u16* __restrict__ out) {
    int i = blockIdx.x * 256 + threadIdx.x;  // over n/4
    float4 v = ((const float4*)in)[i];
    ushort4 o;
    o.x = f2bf(v.x); o.y = f2bf(v.y); o.z = f2bf(v.z); o.w = f2bf(v.w);
    ((ushort4*)out)[i] = o;
}

// ---------- transpose + convert: in fp32 (R,C) -> out bf16 (C,R), z = layer ----------
__global__ __launch_bounds__(256) void k_transpose(const float* __restrict__ in, u16* __restrict__ out, int R, int C) {
    __shared__ float tile[32][33];
    const float* inL = in + (size_t)blockIdx.z * R * C;
    u16* outL = out + (size_t)blockIdx.z * R * C;
    int cb = blockIdx.x * 32, rb = blockIdx.y * 32;
    int tx = threadIdx.x, ty = threadIdx.y;  // (32,8)
#pragma unroll
    for (int i = 0; i < 32; i += 8)
        tile[ty + i][tx] = inL[(size_t)(rb + ty + i) * C + cb + tx];
    __syncthreads();
#pragma unroll
    for (int i = 0; i < 32; i += 8)
        outL[(size_t)(cb + ty + i) * R + rb + tx] = f2bf(tile[tx][ty + i]);
}

// ---------- embedding ----------
__global__ __launch_bounds__(256) void k_embed(const int* __restrict__ ids, const float* __restrict__ emb,
                                               const float* __restrict__ pos, float* __restrict__ x) {
    int i = blockIdx.x * 256 + threadIdx.x;
    int m = i >> 8;
    int d4 = i & 255;
    int t = m & 2047;
    int id = ids[m];
    float4 e = ((const float4*)(emb + (size_t)id * 1024))[d4];
    float4 p = ((const float4*)(pos + (size_t)t * 1024))[d4];
    float4 r; r.x = e.x + p.x; r.y = e.y + p.y; r.z = e.z + p.z; r.w = e.w + p.w;
    ((float4*)(x + (size_t)m * 1024))[d4] = r;
}

// ---------- layernorm: fp32 in (row of 1024) -> bf16 out ----------
__global__ __launch_bounds__(256) void k_ln(const float* __restrict__ in, const float* __restrict__ w,
                                            const float* __restrict__ b, u16* __restrict__ out) {
    int row = blockIdx.x, tid = threadIdx.x;
    float4 v = ((const float4*)(in + (size_t)row * 1024))[tid];
    float s = v.x + v.y + v.z + v.w;
    float ss = v.x * v.x + v.y * v.y + v.z * v.z + v.w * v.w;
    s = wave_sum(s); ss = wave_sum(ss);
    __shared__ float rs[4], rss[4];
    int wid = tid >> 6, lane = tid & 63;
    if (lane == 0) { rs[wid] = s; rss[wid] = ss; }
    __syncthreads();
    s = rs[0] + rs[1] + rs[2] + rs[3];
    ss = rss[0] + rss[1] + rss[2] + rss[3];
    float mu = s * (1.0f / 1024.0f);
    float var = ss * (1.0f / 1024.0f) - mu * mu;
    float inv = rsqrtf(var + 1e-5f);
    float4 wv = ((const float4*)w)[tid], bv = ((const float4*)b)[tid];
    ushort4 o;
    o.x = f2bf((v.x - mu) * inv * wv.x + bv.x);
    o.y = f2bf((v.y - mu) * inv * wv.y + bv.y);
    o.z = f2bf((v.z - mu) * inv * wv.z + bv.z);
    o.w = f2bf((v.w - mu) * inv * wv.w + bv.w);
    *(ushort4*)(out + (size_t)row * 1024 + tid * 4) = o;
}

// ---------- MFMA GEMM: C(M,N) = A(M,K) @ Bt(N,K)^T [+bias][gelu][+res] ----------
template <bool OUT_BF16, bool GELU, bool RES, bool BIAS>
__global__ __launch_bounds__(256, 2) void k_gemm(const u16* __restrict__ A, const u16* __restrict__ Bt,
                                                 const float* __restrict__ bias, const float* __restrict__ res,
                                                 float* __restrict__ outF, u16* __restrict__ outB,
                                                 int M, int N, int K) {
    __shared__ __align__(16) u16 ldsA[128 * 32];
    __shared__ __align__(16) u16 ldsB[128 * 32];
    int tid = threadIdx.x;
    int wave = tid >> 6, lane = tid & 63;
    int quad = lane >> 4, l15 = lane & 15;
    int m0 = blockIdx.y * 128, n0 = blockIdx.x * 128;
    int wm = (wave >> 1) * 64, wn = (wave & 1) * 64;

    f32x4 acc[4][4];
#pragma unroll
    for (int i = 0; i < 4; i++)
#pragma unroll
        for (int j = 0; j < 4; j++) acc[i][j] = (f32x4){0.f, 0.f, 0.f, 0.f};

    int r0 = tid >> 2, c0 = (tid & 3) * 8;
    int r1 = r0 + 64;
    const u16* pa0 = A + (size_t)(m0 + r0) * K + c0;
    const u16* pa1 = A + (size_t)(m0 + r1) * K + c0;
    const u16* pb0 = Bt + (size_t)(n0 + r0) * K + c0;
    const u16* pb1 = Bt + (size_t)(n0 + r1) * K + c0;

    for (int k0 = 0; k0 < K; k0 += 32) {
        uint4 a0 = *(const uint4*)(pa0 + k0);
        uint4 a1 = *(const uint4*)(pa1 + k0);
        uint4 b0 = *(const uint4*)(pb0 + k0);
        uint4 b1 = *(const uint4*)(pb1 + k0);
        __syncthreads();
        *(uint4*)(ldsA + r0 * 32 + c0) = a0;
        *(uint4*)(ldsA + r1 * 32 + c0) = a1;
        *(uint4*)(ldsB + r0 * 32 + c0) = b0;
        *(uint4*)(ldsB + r1 * 32 + c0) = b1;
        __syncthreads();
        bf16x8 af[4], bfr[4];
#pragma unroll
        for (int i = 0; i < 4; i++) af[i] = *(const bf16x8*)(ldsA + (wm + i * 16 + l15) * 32 + quad * 8);
#pragma unroll
        for (int j = 0; j < 4; j++) bfr[j] = *(const bf16x8*)(ldsB + (wn + j * 16 + l15) * 32 + quad * 8);
#pragma unroll
        for (int i = 0; i < 4; i++)
#pragma unroll
            for (int j = 0; j < 4; j++)
                acc[i][j] = __builtin_amdgcn_mfma_f32_16x16x32_bf16(af[i], bfr[j], acc[i][j], 0, 0, 0);
    }

#pragma unroll
    for (int j = 0; j < 4; j++) {
        int col = n0 + wn + j * 16 + l15;
        float bj = BIAS ? bias[col] : 0.f;
#pragma unroll
        for (int i = 0; i < 4; i++) {
#pragma unroll
            for (int r = 0; r < 4; r++) {
                int row = m0 + wm + i * 16 + quad * 4 + r;
                float v = acc[i][j][r] + bj;
                if (GELU) v = 0.5f * v * (1.0f + erff(v * 0.70710678f));
                if (RES) v += res[(size_t)row * N + col];
                if (OUT_BF16) outB[(size_t)row * N + col] = f2bf(v);
                else outF[(size_t)row * N + col] = v;
            }
        }
    }
}

// ---------- MFMA flash attention ----------
// qkv bf16 (B*T, 3072): q at h*64, k at 1024+h*64, v at 2048+h*64. out bf16 (B*T, 1024).
// Block: 256 thr = 4 waves; handles (b,h) x 128 Q rows (wave w -> 32 rows).
// K-tiles of 64. LDS stride 72 (16B-aligned rows, no superbank alias).
__global__ __launch_bounds__(256, 2) void k_attn(const u16* __restrict__ qkv, u16* __restrict__ out) {
    const int b = blockIdx.y >> 4, h = blockIdx.y & 15;
    const int qt = gridDim.x - 1 - blockIdx.x;  // heavy tiles first
    const int q0 = qt * 128;
    const int tid = threadIdx.x;
    const int wave = tid >> 6, lane = tid & 63;
    const int quad = lane >> 4, l15 = lane & 15;
    const int wrow = q0 + wave * 32;

    __shared__ __align__(16) u16 Klds[64 * 72];
    __shared__ __align__(16) u16 Vt[64 * 72];        // Vt[d][krow]
    __shared__ __align__(16) u16 Plds[4][32 * 72];   // wave-private

    const u16* base = qkv + (size_t)b * 2048 * 3072 + h * 64;

    // Q fragments (A-layout): rows wrow+i*16+l15, k = kc*32+quad*8
    bf16x8 qf[2][2];
#pragma unroll
    for (int i = 0; i < 2; i++)
#pragma unroll
        for (int kc = 0; kc < 2; kc++)
            qf[i][kc] = *(const bf16x8*)(base + (size_t)(wrow + i * 16 + l15) * 3072 + kc * 32 + quad * 8);

    f32x4 o[2][4];
#pragma unroll
    for (int i = 0; i < 2; i++)
#pragma unroll
        for (int jd = 0; jd < 4; jd++) o[i][jd] = (f32x4){0.f, 0.f, 0.f, 0.f};
    float mrow[2][4], lrow[2][4];
#pragma unroll
    for (int i = 0; i < 2; i++)
#pragma unroll
        for (int r = 0; r < 4; r++) { mrow[i][r] = -3e38f; lrow[i][r] = 0.f; }

    // staging assignments
    const int kk_ = tid >> 2, kc0 = (tid & 3) * 16;  // K: row kk_, cols kc0..kc0+15
    const int vk = tid & 63, vc = (tid >> 6) * 16;   // V: row vk, cols vc..vc+15 (transposed write)

    const int ktiles = 2 * (qt + 1);
    for (int t = 0; t < ktiles; t++) {
        const int kt = t * 64;
        __syncthreads();
        {
            const u16* kp = base + 1024 + (size_t)(kt + kk_) * 3072 + kc0;
            uint4 a = *(const uint4*)kp;
            uint4 c = *(const uint4*)(kp + 8);
            *(uint4*)(Klds + kk_ * 72 + kc0) = a;
            *(uint4*)(Klds + kk_ * 72 + kc0 + 8) = c;
            const u16* vp = base + 2048 + (size_t)(kt + vk) * 3072 + vc;
            uint4 v0 = *(const uint4*)vp;
            uint4 v1 = *(const uint4*)(vp + 8);
            u16 tmp[16];
            *(uint4*)tmp = v0; *(uint4*)(tmp + 8) = v1;
#pragma unroll
            for (int e = 0; e < 16; e++) Vt[(vc + e) * 72 + vk] = tmp[e];
        }
        __syncthreads();

        if (kt <= wrow + 31) {
            // S = Q @ K^T
            f32x4 s[2][4];
#pragma unroll
            for (int i = 0; i < 2; i++)
#pragma unroll
                for (int j = 0; j < 4; j++) s[i][j] = (f32x4){0.f, 0.f, 0.f, 0.f};
#pragma unroll
            for (int kc = 0; kc < 2; kc++) {
                bf16x8 bf[4];
#pragma unroll
                for (int j = 0; j < 4; j++)
                    bf[j] = *(const bf16x8*)(Klds + (j * 16 + l15) * 72 + kc * 32 + quad * 8);
#pragma unroll
                for (int i = 0; i < 2; i++)
#pragma unroll
                    for (int j = 0; j < 4; j++)
                        s[i][j] = __builtin_amdgcn_mfma_f32_16x16x32_bf16(qf[i][kc], bf[j], s[i][j], 0, 0, 0);
            }
            const bool partial = (kt + 63 > wrow);  // tile crosses the diagonal for this wave
#pragma unroll
            for (int i = 0; i < 2; i++)
#pragma unroll
                for (int j = 0; j < 4; j++)
#pragma unroll
                    for (int r = 0; r < 4; r++) {
                        float v = s[i][j][r] * 0.125f;
                        if (partial) {
                            int row = wrow + i * 16 + quad * 4 + r;
                            int col = kt + j * 16 + l15;
                            if (col > row) v = -3e30f;
                        }
                        s[i][j][r] = v;
                    }
            // online softmax per row (i,r); row constant across the 16-lane col group
            u16* pw = Plds[wave];
#pragma unroll
            for (int i = 0; i < 2; i++)
#pragma unroll
                for (int r = 0; r < 4; r++) {
                    float mx = fmaxf(fmaxf(s[i][0][r], s[i][1][r]), fmaxf(s[i][2][r], s[i][3][r]));
                    mx = fmaxf(mx, __shfl_xor(mx, 1));
                    mx = fmaxf(mx, __shfl_xor(mx, 2));
                    mx = fmaxf(mx, __shfl_xor(mx, 4));
                    mx = fmaxf(mx, __shfl_xor(mx, 8));
                    float mnew = fmaxf(mrow[i][r], mx);
                    float alpha = __expf(mrow[i][r] - mnew);
                    mrow[i][r] = mnew;
                    float psum = 0.f;
#pragma unroll
                    for (int j = 0; j < 4; j++) {
                        float p = __expf(s[i][j][r] - mnew);
                        s[i][j][r] = p;
                        psum += p;
                    }
                    psum += __shfl_xor(psum, 1);
                    psum += __shfl_xor(psum, 2);
                    psum += __shfl_xor(psum, 4);
                    psum += __shfl_xor(psum, 8);
                    lrow[i][r] = lrow[i][r] * alpha + psum;
#pragma unroll
                    for (int jd = 0; jd < 4; jd++) o[i][jd][r] *= alpha;
                }
            // P: C-layout regs -> LDS row-major (stride 72)
#pragma unroll
            for (int i = 0; i < 2; i++)
#pragma unroll
                for (int j = 0; j < 4; j++)
#pragma unroll
                    for (int r = 0; r < 4; r++)
                        pw[(i * 16 + quad * 4 + r) * 72 + j * 16 + l15] = f2bf(s[i][j][r]);
            // PV: A = P (A-layout read from LDS), B = Vt
#pragma unroll
            for (int kc = 0; kc < 2; kc++) {
                bf16x8 pa[2], vb[4];
#pragma unroll
                for (int i = 0; i < 2; i++)
                    pa[i] = *(const bf16x8*)(pw + (i * 16 + l15) * 72 + kc * 32 + quad * 8);
#pragma unroll
                for (int jd = 0; jd < 4; jd++)
                    vb[jd] = *(const bf16x8*)(Vt + (jd * 16 + l15) * 72 + kc * 32 + quad * 8);
#pragma unroll
                for (int i = 0; i < 2; i++)
#pragma unroll
                    for (int jd = 0; jd < 4; jd++)
                        o[i][jd] = __builtin_amdgcn_mfma_f32_16x16x32_bf16(pa[i], vb[jd], o[i][jd], 0, 0, 0);
            }
        }
    }
    // epilogue: out[row][h*64+d] = o / l
#pragma unroll
    for (int i = 0; i < 2; i++)
#pragma unroll
        for (int r = 0; r < 4; r++) {
            float inv = 1.0f / lrow[i][r];
            size_t row = (size_t)(b * 2048 + wrow + i * 16 + quad * 4 + r);
#pragma unroll
            for (int jd = 0; jd < 4; jd++)
                out[row * 1024 + h * 64 + jd * 16 + l15] = f2bf(o[i][jd][r] * inv);
        }
}

// ---------- CE per row ----------
__global__ __launch_bounds__(256) void k_ce(const float* __restrict__ logits, const int* __restrict__ targets,
                                            float* __restrict__ ce) {
    int row = blockIdx.x, tid = threadIdx.x;
    const float4* lr = (const float4*)(logits + (size_t)row * 4096);
    float4 v[4];
#pragma unroll
    for (int c = 0; c < 4; c++) v[c] = lr[tid + c * 256];
    float mx = -3e38f;
#pragma unroll
    for (int c = 0; c < 4; c++) mx = fmaxf(mx, fmaxf(fmaxf(v[c].x, v[c].y), fmaxf(v[c].z, v[c].w)));
#pragma unroll
    for (int off = 32; off; off >>= 1) mx = fmaxf(mx, __shfl_xor(mx, off));
    __shared__ float rm[4], rsum[4];
    int wid = tid >> 6, lane = tid & 63;
    if (lane == 0) rm[wid] = mx;
    __syncthreads();
    mx = fmaxf(fmaxf(rm[0], rm[1]), fmaxf(rm[2], rm[3]));
    float se = 0.f;
#pragma unroll
    for (int c = 0; c < 4; c++)
        se += __expf(v[c].x - mx) + __expf(v[c].y - mx) + __expf(v[c].z - mx) + __expf(v[c].w - mx);
#pragma unroll
    for (int off = 32; off; off >>= 1) se += __shfl_xor(se, off);
    if (lane == 0) rsum[wid] = se;
    __syncthreads();
    if (tid == 0) {
        se = rsum[0] + rsum[1] + rsum[2] + rsum[3];
        int tgt = targets[row];
        float nll = -(logits[(size_t)row * 4096 + tgt] - mx - logf(se));
        ce[row] = (tgt == 0) ? 0.f : nll;
    }
}

// ---------- final loss ----------
__global__ __launch_bounds__(256) void k_loss(const float* __restrict__ ce, const int* __restrict__ vmask,
                                              float* __restrict__ out) {
    int tid = threadIdx.x;
    int wid = tid >> 6, lane = tid & 63;
    int bad = 0;
    for (int i = tid; i < 2048; i += 256) {
        unsigned int w = ((const unsigned int*)vmask)[i];
        if (w > 1u) bad = 1;
    }
#pragma unroll
    for (int off = 32; off; off >>= 1) bad |= __shfl_xor(bad, off);
    __shared__ int sb[4];
    if (lane == 0) sb[wid] = bad;
    __syncthreads();
    bad = sb[0] | sb[1] | sb[2] | sb[3];

    float s1 = 0.f, s2 = 0.f;
    if (bad) {
        const unsigned char* mb = (const unsigned char*)vmask;
        for (int i = tid; i < 8192; i += 256) {
            float w = 1.0f + 4.0f * (mb[i] != 0);
            s1 += ce[i] * w; s2 += w;
        }
    } else {
        for (int i = tid; i < 8192; i += 256) {
            float w = 1.0f + 4.0f * (vmask[i] != 0);
            s1 += ce[i] * w; s2 += w;
        }
    }
#pragma unroll
    for (int off = 32; off; off >>= 1) { s1 += __shfl_down(s1, off); s2 += __shfl_down(s2, off); }
    __shared__ float r1[4], r2[4];
    if (lane == 0) { r1[wid] = s1; r2[wid] = s2; }
    __syncthreads();
    if (tid == 0) out[0] = (r1[0] + r1[1] + r1[2] + r1[3]) / (r2[0] + r2[1] + r2[2] + r2[3]);
}

extern "C" void kernel_launch(void* const* d_in, const int* in_sizes, int n_in,
                              void* d_out, int out_size, void* d_ws, size_t ws_size,
                              hipStream_t stream) {
    const int* input_ids = (const int*)d_in[0];
    const int* targets = (const int*)d_in[1];
    const int* vmask = (const int*)d_in[2];
    const float* token_emb = (const float*)d_in[3];
    const float* pos_emb = (const float*)d_in[4];
    const float* ln1_w = (const float*)d_in[5];
    const float* ln1_b = (const float*)d_in[6];
    const float* wqkv = (const float*)d_in[7];
    const float* bqkv = (const float*)d_in[8];
    const float* wproj = (const float*)d_in[9];
    const float* bproj = (const float*)d_in[10];
    const float* ln2_w = (const float*)d_in[11];
    const float* ln2_b = (const float*)d_in[12];
    const float* w1 = (const float*)d_in[13];
    const float* b1 = (const float*)d_in[14];
    const float* w2 = (const float*)d_in[15];
    const float* b2 = (const float*)d_in[16];
    const float* lnf_w = (const float*)d_in[17];
    const float* lnf_b = (const float*)d_in[18];

    char* p = (char*)d_ws;
    u16* embb = (u16*)p;   p += (size_t)4096 * 1024 * 2;
    u16* wqkvt = (u16*)p;  p += (size_t)8 * 3072 * 1024 * 2;
    u16* wprojt = (u16*)p; p += (size_t)8 * 1024 * 1024 * 2;
    u16* w1t = (u16*)p;    p += (size_t)8 * 4096 * 1024 * 2;
    u16* w2t = (u16*)p;    p += (size_t)8 * 1024 * 4096 * 2;
    float* xw = (float*)p; p += (size_t)8192 * 1024 * 4;
    u16* hb = (u16*)p;     p += (size_t)8192 * 1024 * 2;
    u16* qkvb = (u16*)p;   p += (size_t)8192 * 3072 * 2;
    u16* attnb = (u16*)p;  p += (size_t)8192 * 1024 * 2;
    u16* ffb = (u16*)p;    p += (size_t)8192 * 4096 * 2;
    float* cerow = (float*)p; p += 8192 * 4;

    float* logits = (float*)d_out;

    k_cvt<<<4096, 256, 0, stream>>>(token_emb, embb);
    dim3 tb(32, 8);
    k_transpose<<<dim3(96, 32, 8), tb, 0, stream>>>(wqkv, wqkvt, 1024, 3072);
    k_transpose<<<dim3(32, 32, 8), tb, 0, stream>>>(wproj, wprojt, 1024, 1024);
    k_transpose<<<dim3(128, 32, 8), tb, 0, stream>>>(w1, w1t, 1024, 4096);
    k_transpose<<<dim3(32, 128, 8), tb, 0, stream>>>(w2, w2t, 4096, 1024);

    k_embed<<<8192, 256, 0, stream>>>(input_ids, token_emb, pos_emb, xw);

    for (int l = 0; l < 8; l++) {
        k_ln<<<8192, 256, 0, stream>>>(xw, ln1_w + l * 1024, ln1_b + l * 1024, hb);
        k_gemm<true, false, false, true><<<dim3(24, 64), 256, 0, stream>>>(
            hb, wqkvt + (size_t)l * 3072 * 1024, bqkv + l * 3072, nullptr, nullptr, qkvb, 8192, 3072, 1024);
        k_attn<<<dim3(16, 64), 256, 0, stream>>>(qkvb, attnb);
        k_gemm<false, false, true, true><<<dim3(8, 64), 256, 0, stream>>>(
            attnb, wprojt + (size_t)l * 1024 * 1024, bproj + l * 1024, xw, xw, nullptr, 8192, 1024, 1024);
        k_ln<<<8192, 256, 0, stream>>>(xw, ln2_w + l * 1024, ln2_b + l * 1024, hb);
        k_gemm<true, true, false, true><<<dim3(32, 64), 256, 0, stream>>>(
            hb, w1t + (size_t)l * 4096 * 1024, b1 + l * 4096, nullptr, nullptr, ffb, 8192, 4096, 1024);
        k_gemm<false, false, true, true><<<dim3(8, 64), 256, 0, stream>>>(
            ffb, w2t + (size_t)l * 1024 * 4096, b2 + l * 1024, xw, xw, nullptr, 8192, 1024, 4096);
    }

    k_ln<<<8192, 256, 0, stream>>>(xw, lnf_w, lnf_b, hb);
    k_gemm<false, false, false, false><<<dim3(32, 64), 256, 0, stream>>>(
        hb, embb, nullptr, nullptr, logits, nullptr, 8192, 4096, 1024);

    k_ce<<<8192, 256, 0, stream>>>(logits, targets, cerow);
    k_loss<<<1, 256, 0, stream>>>(cerow, vmask, logits + (size_t)8192 * 4096);
}